// Round 2
// baseline (853.578 us; speedup 1.0000x reference)
//
#include <hip/hip_runtime.h>
#include <hip/hip_bf16.h>

#define N_NODES 100000
#define N_EDGES 600000
#define DIM 128
#define EDIM 32

// ---------------------------------------------------------------------------
// Edge kernel: msg[e] = x[j[e]] + edge_attr[e] @ We + be ; agg[i[e]] += msg
// One block = 128 threads handles 32 edges. We (32x128) staged in LDS.
// ---------------------------------------------------------------------------
__global__ __launch_bounds__(128) void gine_edge_kernel(
    const float* __restrict__ x,
    const int* __restrict__ eidx,          // [2*E]: row0 = i (dst), row1 = j (src)
    const float* __restrict__ eattr,
    const float* __restrict__ We,
    const float* __restrict__ be,
    float* __restrict__ agg)
{
    __shared__ float We_s[EDIM * DIM];   // 16 KB
    __shared__ float ea_s[32 * EDIM];    // 4 KB
    __shared__ int ii_s[32];
    __shared__ int jj_s[32];

    const int tid = threadIdx.x;   // 0..127 == output dim d
    for (int r = tid; r < EDIM * DIM; r += 128) We_s[r] = We[r];
    const float be_d = be[tid];

    const int e0 = blockIdx.x * 32;
    for (int r = tid; r < 32 * EDIM; r += 128) ea_s[r] = eattr[e0 * EDIM + r];
    if (tid < 32) {
        ii_s[tid] = eidx[e0 + tid];
        jj_s[tid] = eidx[N_EDGES + e0 + tid];
    }
    __syncthreads();

    for (int t = 0; t < 32; ++t) {
        float acc = be_d;
        const float* ea = &ea_s[t * EDIM];
        #pragma unroll
        for (int k = 0; k < EDIM; ++k)
            acc += ea[k] * We_s[k * DIM + tid];   // ea: LDS broadcast; We: 2-way (free)
        acc += x[jj_s[t] * DIM + tid];            // coalesced f32 gather
        atomicAdd(&agg[ii_s[t] * DIM + tid], acc);
    }
}

// ---------------------------------------------------------------------------
// MLP layer 1: r = relu(((1+eps)*x + agg) @ W1 + b1), written in-place to agg.
// 256 threads = 2 nodes/iteration. W1 staged in LDS (64 KB).
// ---------------------------------------------------------------------------
__global__ __launch_bounds__(256) void gine_mlp1_kernel(
    const float* __restrict__ x,
    const float* __restrict__ W1,
    const float* __restrict__ b1,
    const float* __restrict__ epsp,
    float* __restrict__ agg)
{
    __shared__ float W_s[DIM * DIM];     // 64 KB
    __shared__ float h_s[2][DIM];

    const int tid = threadIdx.x;
    const int slot = tid >> 7;           // which of the 2 nodes
    const int d = tid & 127;

    for (int q = tid; q < DIM * DIM; q += 256) W_s[q] = W1[q];
    const float b1_d = b1[d];
    const float epv = 1.0f + epsp[0];
    __syncthreads();

    const int npairs = N_NODES / 2;      // 100000 is even
    for (int p = blockIdx.x; p < npairs; p += gridDim.x) {
        const int n = p * 2 + slot;
        h_s[slot][d] = epv * x[n * DIM + d] + agg[n * DIM + d];
        __syncthreads();
        const float* h = h_s[slot];
        float acc0 = 0.f, acc1 = 0.f;
        #pragma unroll
        for (int k = 0; k < DIM; k += 2) {
            acc0 += h[k]     * W_s[k * DIM + d];
            acc1 += h[k + 1] * W_s[(k + 1) * DIM + d];
        }
        agg[n * DIM + d] = fmaxf(acc0 + acc1 + b1_d, 0.f);
        __syncthreads();
    }
}

// ---------------------------------------------------------------------------
// MLP layer 2 + LayerNorm: out = LN(r @ W2 + b2) * gamma + beta
// ---------------------------------------------------------------------------
__global__ __launch_bounds__(256) void gine_mlp2_kernel(
    const float* __restrict__ r,
    const float* __restrict__ W2,
    const float* __restrict__ b2v,
    const float* __restrict__ gamma,
    const float* __restrict__ beta,
    float* __restrict__ out)
{
    __shared__ float W_s[DIM * DIM];     // 64 KB
    __shared__ float h_s[2][DIM];
    __shared__ float red_s[2][2][2];     // [slot][wave-in-slot][sum, sumsq]

    const int tid = threadIdx.x;
    const int slot = tid >> 7;
    const int d = tid & 127;
    const int wv = (tid >> 6) & 1;
    const int lane = tid & 63;

    for (int q = tid; q < DIM * DIM; q += 256) W_s[q] = W2[q];
    const float b2_d = b2v[d];
    const float g_d = gamma[d];
    const float bt_d = beta[d];
    __syncthreads();

    const int npairs = N_NODES / 2;
    for (int p = blockIdx.x; p < npairs; p += gridDim.x) {
        const int n = p * 2 + slot;
        h_s[slot][d] = r[n * DIM + d];
        __syncthreads();
        const float* h = h_s[slot];
        float acc0 = 0.f, acc1 = 0.f;
        #pragma unroll
        for (int k = 0; k < DIM; k += 2) {
            acc0 += h[k]     * W_s[k * DIM + d];
            acc1 += h[k + 1] * W_s[(k + 1) * DIM + d];
        }
        float o = acc0 + acc1 + b2_d;

        // LayerNorm over 128 dims = 2 waves: shuffle-reduce then LDS combine.
        float s = o, ss = o * o;
        #pragma unroll
        for (int off = 32; off > 0; off >>= 1) {
            s  += __shfl_down(s, off, 64);
            ss += __shfl_down(ss, off, 64);
        }
        if (lane == 0) { red_s[slot][wv][0] = s; red_s[slot][wv][1] = ss; }
        __syncthreads();
        const float sum   = red_s[slot][0][0] + red_s[slot][1][0];
        const float sumsq = red_s[slot][0][1] + red_s[slot][1][1];
        const float mu  = sum * (1.0f / DIM);
        const float var = sumsq * (1.0f / DIM) - mu * mu;
        const float inv = rsqrtf(var + 1e-5f);
        out[n * DIM + d] = (o - mu) * inv * g_d + bt_d;
        __syncthreads();
    }
}

extern "C" void kernel_launch(void* const* d_in, const int* in_sizes, int n_in,
                              void* d_out, int out_size, void* d_ws, size_t ws_size,
                              hipStream_t stream) {
    const float* x     = (const float*)d_in[0];
    const int*   eidx  = (const int*)d_in[1];
    const float* eattr = (const float*)d_in[2];
    const float* We    = (const float*)d_in[3];
    const float* be    = (const float*)d_in[4];
    const float* W1    = (const float*)d_in[5];
    const float* b1    = (const float*)d_in[6];
    const float* W2    = (const float*)d_in[7];
    const float* b2v   = (const float*)d_in[8];
    const float* eps   = (const float*)d_in[9];
    const float* gamma = (const float*)d_in[10];
    const float* beta  = (const float*)d_in[11];
    float* out = (float*)d_out;

    float* agg = (float*)d_ws;   // N*DIM f32 = 51.2 MB; re-poisoned each call
    hipMemsetAsync(agg, 0, (size_t)N_NODES * DIM * sizeof(float), stream);

    gine_edge_kernel<<<N_EDGES / 32, 128, 0, stream>>>(x, eidx, eattr, We, be, agg);
    gine_mlp1_kernel<<<512, 256, 0, stream>>>(x, W1, b1, eps, agg);
    gine_mlp2_kernel<<<512, 256, 0, stream>>>(agg, W2, b2v, gamma, beta, out);
}

// Round 3
// 612.949 us; speedup vs baseline: 1.3926x; 1.3926x over previous
//
#include <hip/hip_runtime.h>
#include <hip/hip_bf16.h>

#define N_NODES 100000
#define N_EDGES 600000
#define DIM 128
#define EDIM 32

typedef __attribute__((ext_vector_type(8))) short bf16x8;
typedef __attribute__((ext_vector_type(4))) float f32x4;

static __device__ __forceinline__ short f2bf(float v) {
    __hip_bfloat16 h = __float2bfloat16(v);
    return *(short*)&h;
}

// ---------------------------------------------------------------------------
// Edge kernel: msg[e] = x[j[e]] + edge_attr[e] @ We + be ; agg[i[e]] += msg
// 128 threads / 128 edges per block. We (32x128) + 128 edge attrs in LDS.
// ---------------------------------------------------------------------------
__global__ __launch_bounds__(128) void gine_edge_kernel(
    const float* __restrict__ x,
    const int* __restrict__ eidx,          // [2*E]: row0 = i (dst), row1 = j (src)
    const float* __restrict__ eattr,
    const float* __restrict__ We,
    const float* __restrict__ be,
    float* __restrict__ agg)
{
    __shared__ float We_s[EDIM * DIM];     // 16 KB
    __shared__ float ea_s[128 * EDIM];     // 16 KB
    __shared__ int ii_s[128];
    __shared__ int jj_s[128];

    const int tid = threadIdx.x;           // == output dim d
    for (int r = tid; r < EDIM * DIM; r += 128) We_s[r] = We[r];

    const int e0 = blockIdx.x * 128;
    const int nE = min(128, N_EDGES - e0);

    // stage edge attrs as float4 (nE*32 floats = nE*8 float4)
    const float4* ea_g = (const float4*)(eattr + (size_t)e0 * EDIM);
    for (int r = tid; r < nE * 8; r += 128) ((float4*)ea_s)[r] = ea_g[r];
    if (tid < nE) {
        ii_s[tid] = eidx[e0 + tid];
        jj_s[tid] = eidx[N_EDGES + e0 + tid];
    }
    __syncthreads();

    const float be_d = be[tid];

    // depth-2 software pipeline on the x gather
    float xc = x[(size_t)jj_s[0] * DIM + tid];
    float xn = (1 < nE) ? x[(size_t)jj_s[1] * DIM + tid] : 0.f;

    for (int t = 0; t < nE; ++t) {
        float xf = (t + 2 < nE) ? x[(size_t)jj_s[t + 2] * DIM + tid] : 0.f;
        float acc = be_d + xc;
        const float4* ea = (const float4*)&ea_s[t * EDIM];
        #pragma unroll
        for (int k4 = 0; k4 < 8; ++k4) {
            float4 e = ea[k4];           // wave-uniform address -> LDS broadcast
            acc += e.x * We_s[(k4 * 4 + 0) * DIM + tid];
            acc += e.y * We_s[(k4 * 4 + 1) * DIM + tid];
            acc += e.z * We_s[(k4 * 4 + 2) * DIM + tid];
            acc += e.w * We_s[(k4 * 4 + 3) * DIM + tid];
        }
        atomicAdd(&agg[(size_t)ii_s[t] * DIM + tid], acc);
        xc = xn; xn = xf;
    }
}

// ---------------------------------------------------------------------------
// Fused MLP1 + MLP2 + LayerNorm using bf16 MFMA 16x16x32.
// Block = 256 thr (4 waves). Each wave owns a 16-node tile per iteration.
// W1/W2 pre-packed in LDS in B-fragment order; h staged per-wave in LDS
// row-major bf16 (A-fragment readable); L1->L2 via wave-private LDS
// transpose (C-layout -> A-layout); LN via shfl_xor over 16-lane groups.
// ---------------------------------------------------------------------------
#define HROW_STRIDE 136   // 128 + 8 bf16 pad (keeps 16B alignment, breaks bank stride)

__global__ __launch_bounds__(256) void gine_mlp_fused(
    const float* __restrict__ x,
    const float* __restrict__ agg,
    const float* __restrict__ W1,
    const float* __restrict__ b1,
    const float* __restrict__ W2,
    const float* __restrict__ b2,
    const float* __restrict__ epsp,
    const float* __restrict__ gamma,
    const float* __restrict__ beta,
    float* __restrict__ out)
{
    __shared__ short Wp[2][16384];          // 64 KB: [layer][(dt*4+kc)*64+lane][8]
    __shared__ short hrow[4][16 * HROW_STRIDE];  // 17 KB: per-wave node rows

    const int tid  = threadIdx.x;
    const int wave = tid >> 6;
    const int lane = tid & 63;
    const int m    = lane & 15;             // col-in-tile / node-in-A
    const int g    = lane >> 4;             // quad index

    // ---- pack W1/W2 fragments: Wp[l][s*64+lane] holds B[k=kc*32+g*8+j][n=dt*16+m]
    for (int s = wave * 8; s < wave * 8 + 8; ++s) {
        const int dt = s >> 2, kc = s & 3;
        const int krow = kc * 32 + g * 8;
        const int col  = dt * 16 + m;
        short p1[8], p2[8];
        #pragma unroll
        for (int j = 0; j < 8; ++j) {
            p1[j] = f2bf(W1[(size_t)(krow + j) * DIM + col]);
            p2[j] = f2bf(W2[(size_t)(krow + j) * DIM + col]);
        }
        #pragma unroll
        for (int j = 0; j < 8; ++j) {
            Wp[0][(s * 64 + lane) * 8 + j] = p1[j];
            Wp[1][(s * 64 + lane) * 8 + j] = p2[j];
        }
    }

    // per-lane epilogue constants (dim = dt*16 + m)
    float b1v[8], b2v[8], gv[8], btv[8];
    #pragma unroll
    for (int dt = 0; dt < 8; ++dt) {
        const int d = dt * 16 + m;
        b1v[dt] = b1[d]; b2v[dt] = b2[d]; gv[dt] = gamma[d]; btv[dt] = beta[d];
    }
    const float epv = 1.0f + epsp[0];
    __syncthreads();

    short* myrow = &hrow[wave][0];
    const int ntiles = N_NODES / 16;        // 6250

    for (int tile = blockIdx.x * 4 + wave; tile < ntiles; tile += gridDim.x * 4) {
        const int nbase = tile * 16;

        // ---- stage h = (1+eps)*x + agg as bf16 rows [16][128] (padded)
        #pragma unroll
        for (int r = 0; r < 8; ++r) {
            const int idx4 = r * 64 + lane;          // 512 float4 = 16 nodes x 32
            const int node = idx4 >> 5, dq = idx4 & 31;
            const size_t goff = ((size_t)(nbase + node) * DIM + dq * 4) / 4;
            float4 xv = ((const float4*)x)[goff];
            float4 av = ((const float4*)agg)[goff];
            short4 hv;
            hv.x = f2bf(epv * xv.x + av.x);
            hv.y = f2bf(epv * xv.y + av.y);
            hv.z = f2bf(epv * xv.z + av.z);
            hv.w = f2bf(epv * xv.w + av.w);
            *(short4*)&myrow[node * HROW_STRIDE + dq * 4] = hv;
        }
        __asm__ volatile("s_waitcnt lgkmcnt(0)" ::: "memory");

        // ---- layer 1: acc[dt] = h @ W1 (16 nodes x 128 dims)
        f32x4 acc[8];
        #pragma unroll
        for (int dt = 0; dt < 8; ++dt) acc[dt] = (f32x4){0.f, 0.f, 0.f, 0.f};
        #pragma unroll
        for (int kc = 0; kc < 4; ++kc) {
            bf16x8 afrag = *(bf16x8*)&myrow[m * HROW_STRIDE + kc * 32 + g * 8];
            #pragma unroll
            for (int dt = 0; dt < 8; ++dt) {
                bf16x8 bfrag = *(bf16x8*)&Wp[0][((dt * 4 + kc) * 64 + lane) * 8];
                acc[dt] = __builtin_amdgcn_mfma_f32_16x16x32_bf16(afrag, bfrag, acc[dt], 0, 0, 0);
            }
        }
        __asm__ volatile("s_waitcnt lgkmcnt(0)" ::: "memory");  // A-reads done before overwrite

        // ---- relu(acc + b1) -> myrow rows (C-layout: node=g*4+q, dim=dt*16+m)
        #pragma unroll
        for (int dt = 0; dt < 8; ++dt)
            #pragma unroll
            for (int q = 0; q < 4; ++q) {
                float v = fmaxf(acc[dt][q] + b1v[dt], 0.f);
                myrow[(g * 4 + q) * HROW_STRIDE + dt * 16 + m] = f2bf(v);
            }
        __asm__ volatile("s_waitcnt lgkmcnt(0)" ::: "memory");

        // ---- layer 2
        #pragma unroll
        for (int dt = 0; dt < 8; ++dt) acc[dt] = (f32x4){0.f, 0.f, 0.f, 0.f};
        #pragma unroll
        for (int kc = 0; kc < 4; ++kc) {
            bf16x8 afrag = *(bf16x8*)&myrow[m * HROW_STRIDE + kc * 32 + g * 8];
            #pragma unroll
            for (int dt = 0; dt < 8; ++dt) {
                bf16x8 bfrag = *(bf16x8*)&Wp[1][((dt * 4 + kc) * 64 + lane) * 8];
                acc[dt] = __builtin_amdgcn_mfma_f32_16x16x32_bf16(afrag, bfrag, acc[dt], 0, 0, 0);
            }
        }

        // ---- bias + LayerNorm. Lane holds (dt,q): node g*4+q, dim dt*16+m.
        float s[4] = {0, 0, 0, 0}, ss[4] = {0, 0, 0, 0};
        #pragma unroll
        for (int dt = 0; dt < 8; ++dt)
            #pragma unroll
            for (int q = 0; q < 4; ++q) {
                float o = acc[dt][q] + b2v[dt];
                acc[dt][q] = o;
                s[q] += o; ss[q] += o * o;
            }
        #pragma unroll
        for (int mask = 1; mask < 16; mask <<= 1)
            #pragma unroll
            for (int q = 0; q < 4; ++q) {
                s[q]  += __shfl_xor(s[q], mask, 64);
                ss[q] += __shfl_xor(ss[q], mask, 64);
            }
        float mu[4], inv[4];
        #pragma unroll
        for (int q = 0; q < 4; ++q) {
            mu[q] = s[q] * (1.0f / DIM);
            float var = ss[q] * (1.0f / DIM) - mu[q] * mu[q];
            inv[q] = rsqrtf(var + 1e-5f);
        }
        #pragma unroll
        for (int dt = 0; dt < 8; ++dt)
            #pragma unroll
            for (int q = 0; q < 4; ++q) {
                const int node = nbase + g * 4 + q;
                out[(size_t)node * DIM + dt * 16 + m] =
                    (acc[dt][q] - mu[q]) * inv[q] * gv[dt] + btv[dt];
            }
    }
}

extern "C" void kernel_launch(void* const* d_in, const int* in_sizes, int n_in,
                              void* d_out, int out_size, void* d_ws, size_t ws_size,
                              hipStream_t stream) {
    const float* x     = (const float*)d_in[0];
    const int*   eidx  = (const int*)d_in[1];
    const float* eattr = (const float*)d_in[2];
    const float* We    = (const float*)d_in[3];
    const float* be    = (const float*)d_in[4];
    const float* W1    = (const float*)d_in[5];
    const float* b1    = (const float*)d_in[6];
    const float* W2    = (const float*)d_in[7];
    const float* b2v   = (const float*)d_in[8];
    const float* eps   = (const float*)d_in[9];
    const float* gamma = (const float*)d_in[10];
    const float* beta  = (const float*)d_in[11];
    float* out = (float*)d_out;

    float* agg = (float*)d_ws;   // N*DIM f32 = 51.2 MB; re-poisoned each call
    hipMemsetAsync(agg, 0, (size_t)N_NODES * DIM * sizeof(float), stream);

    gine_edge_kernel<<<(N_EDGES + 127) / 128, 128, 0, stream>>>(x, eidx, eattr, We, be, agg);
    gine_mlp_fused<<<512, 256, 0, stream>>>(x, agg, W1, b1, W2, b2v, eps, gamma, beta, out);
}